// Round 1
// baseline (422.607 us; speedup 1.0000x reference)
//
#include <hip/hip_runtime.h>
#include <stdint.h>

typedef __bf16 bf16_t;
typedef __bf16 bf16x8 __attribute__((ext_vector_type(8)));
typedef float f32x4 __attribute__((ext_vector_type(4)));

#define N_NODES  50000
#define N_EDGES  400000
#define D_IN     512
#define D_HID    512
#define D_OUTD   256
#define M_PAD    50048   // 391 * 128 (GEMM M padded; pad rows zeroed)
#define NB_SCAN  196     // ceil(50000/256)

// ---------- helpers ----------
__device__ __forceinline__ uint32_t f2bf_bits(float x){
    uint32_t u = __float_as_uint(x);
    return (u + 0x7fffu + ((u >> 16) & 1u)) >> 16;   // RNE
}
__device__ __forceinline__ void unpack8(uint4 v, float* f){
    f[0]=__uint_as_float(v.x<<16); f[1]=__uint_as_float(v.x & 0xffff0000u);
    f[2]=__uint_as_float(v.y<<16); f[3]=__uint_as_float(v.y & 0xffff0000u);
    f[4]=__uint_as_float(v.z<<16); f[5]=__uint_as_float(v.z & 0xffff0000u);
    f[6]=__uint_as_float(v.w<<16); f[7]=__uint_as_float(v.w & 0xffff0000u);
}
__device__ __forceinline__ void unpack4(uint2 v, float* f){
    f[0]=__uint_as_float(v.x<<16); f[1]=__uint_as_float(v.x & 0xffff0000u);
    f[2]=__uint_as_float(v.y<<16); f[3]=__uint_as_float(v.y & 0xffff0000u);
}
__device__ __forceinline__ void glds16(const bf16_t* g, bf16_t* l){
    __builtin_amdgcn_global_load_lds(
        (const __attribute__((address_space(1))) uint32_t*)g,
        (__attribute__((address_space(3))) uint32_t*)l, 16, 0, 0);
}

// ---------- dtype conversion ----------
__global__ __launch_bounds__(256)
void conv_x_bf16(const float* __restrict__ x, bf16_t* __restrict__ Xb){
    const int t = blockIdx.x * 256 + threadIdx.x;   // 4 elements per thread
    const int row = t >> 7;                          // (4t)/512
    uint2 o;
    if (row < N_NODES){
        float4 v = ((const float4*)x)[t];
        o.x = f2bf_bits(v.x) | (f2bf_bits(v.y) << 16);
        o.y = f2bf_bits(v.z) | (f2bf_bits(v.w) << 16);
    } else { o.x = 0u; o.y = 0u; }                   // zero pad rows
    ((uint2*)Xb)[t] = o;
}

// Wt[n][k] = bf16(W[k][n]); K fixed 512, ncols = N of W
__global__ __launch_bounds__(256)
void conv_w_t(const float* __restrict__ W, bf16_t* __restrict__ Wt, int ncols){
    const int idx = blockIdx.x * 256 + threadIdx.x;  // n*512 + k
    const int n = idx >> 9;
    const int k = idx & 511;
    Wt[idx] = (bf16_t)W[k * ncols + n];
}

// ---------- degree / CSR build ----------
__global__ __launch_bounds__(256)
void k_init_deg(int* __restrict__ deg){
    int i = blockIdx.x*256 + threadIdx.x;
    if (i < N_NODES) deg[i] = 1;                     // self-loop
}
__global__ __launch_bounds__(256)
void k_count(const int* __restrict__ ei, int* __restrict__ deg){
    int e = blockIdx.x*256 + threadIdx.x;
    if (e < N_EDGES) atomicAdd(&deg[ei[N_EDGES + e]], 1);
}
__global__ __launch_bounds__(256)
void k_dinv(const int* __restrict__ deg, float* __restrict__ dinv){
    int i = blockIdx.x*256 + threadIdx.x;
    if (i < N_NODES) dinv[i] = rsqrtf((float)deg[i]);
}
// block-local exclusive scan of (deg-1)
__global__ __launch_bounds__(256)
void k_scan_block(const int* __restrict__ deg, int* __restrict__ part,
                  int* __restrict__ bsum, int n){
    __shared__ int tmp[256];
    int i = blockIdx.x*256 + threadIdx.x;
    int v = (i < n) ? (deg[i] - 1) : 0;
    tmp[threadIdx.x] = v;
    __syncthreads();
    for (int off = 1; off < 256; off <<= 1){
        int t = (threadIdx.x >= off) ? tmp[threadIdx.x - off] : 0;
        __syncthreads();
        tmp[threadIdx.x] += t;
        __syncthreads();
    }
    if (i < n) part[i] = tmp[threadIdx.x] - v;
    if (threadIdx.x == 255) bsum[blockIdx.x] = tmp[255];
}
__global__ __launch_bounds__(256)
void k_scan_bsum(const int* __restrict__ bsum, int* __restrict__ bsum2, int nb){
    __shared__ int tmp[256];
    int v = (threadIdx.x < nb) ? bsum[threadIdx.x] : 0;
    tmp[threadIdx.x] = v;
    __syncthreads();
    for (int off = 1; off < 256; off <<= 1){
        int t = (threadIdx.x >= off) ? tmp[threadIdx.x - off] : 0;
        __syncthreads();
        tmp[threadIdx.x] += t;
        __syncthreads();
    }
    if (threadIdx.x < nb) bsum2[threadIdx.x] = tmp[threadIdx.x] - v;
}
__global__ __launch_bounds__(256)
void k_finalize_rowptr(const int* __restrict__ part, const int* __restrict__ bsum2,
                       int* __restrict__ rowp, int* __restrict__ cursor, int n){
    int i = blockIdx.x*256 + threadIdx.x;
    if (i < n){ int r = part[i] + bsum2[blockIdx.x]; rowp[i] = r; cursor[i] = r; }
    if (i == 0) rowp[n] = N_EDGES;
}
__global__ __launch_bounds__(256)
void k_place(const int* __restrict__ ei, const float* __restrict__ dinv,
             int* __restrict__ cursor, int* __restrict__ csrc, float* __restrict__ cnorm){
    int e = blockIdx.x*256 + threadIdx.x;
    if (e < N_EDGES){
        int s = ei[e];
        int d = ei[N_EDGES + e];
        int p = atomicAdd(&cursor[d], 1);
        csrc[p]  = s;
        cnorm[p] = dinv[s] * dinv[d];
    }
}

// ---------- bf16 MFMA GEMM: C[M_PAD][N] = A[M_PAD][K] @ Bt[N][K]^T ----------
// 128x128 tile, BK=32, 256 threads = 4 waves in 2x2, each wave 64x64 (4x4 MFMA 16x16x32)
__global__ __launch_bounds__(256, 2)
void gemm_bf16_mfma(const bf16_t* __restrict__ A, const bf16_t* __restrict__ Bt,
                    bf16_t* __restrict__ C, int N, int K)
{
    __shared__ bf16_t As[128*32];   // [m][k], 8 KB
    __shared__ bf16_t Bs[128*32];   // [n][k], 8 KB

    const int tid  = threadIdx.x;
    const int wave = tid >> 6;
    const int lane = tid & 63;
    const int wr = wave >> 1;
    const int wc = wave & 1;
    const int mBase = blockIdx.x * 128;
    const int nBase = blockIdx.y * 128;

    // staging: wave-uniform LDS base + lane*16B; lane l -> row base+l/4, k-part (l%4)*8
    const int srow = lane >> 2;
    const int scol = (lane & 3) << 3;
    const bf16_t* Ag0 = A  + (size_t)(mBase + wave*16 + srow) * K + scol;
    const bf16_t* Ag1 = Ag0 + (size_t)64 * K;
    const bf16_t* Bg0 = Bt + (size_t)(nBase + wave*16 + srow) * K + scol;
    const bf16_t* Bg1 = Bg0 + (size_t)64 * K;
    bf16_t* As0 = &As[wave*512];
    bf16_t* As1 = &As[wave*512 + 64*32];
    bf16_t* Bs0 = &Bs[wave*512];
    bf16_t* Bs1 = &Bs[wave*512 + 64*32];

    // fragment addressing: A[m=lane&15][k=q*8+j], B[k=q*8+j][n=lane&15]
    const int m16 = lane & 15;
    const int q   = lane >> 4;
    const bf16_t* aP = &As[(wr*64 + m16)*32 + q*8];
    const bf16_t* bP = &Bs[(wc*64 + m16)*32 + q*8];

    f32x4 acc[4][4] = {};

    for (int k0 = 0; k0 < K; k0 += 32){
        glds16(Ag0 + k0, As0);
        glds16(Ag1 + k0, As1);
        glds16(Bg0 + k0, Bs0);
        glds16(Bg1 + k0, Bs1);
        __syncthreads();           // drains vmcnt for global_load_lds
        bf16x8 a[4], b[4];
        #pragma unroll
        for (int t = 0; t < 4; ++t){
            a[t] = *(const bf16x8*)(aP + t*16*32);
            b[t] = *(const bf16x8*)(bP + t*16*32);
        }
        #pragma unroll
        for (int i = 0; i < 4; ++i){
            #pragma unroll
            for (int j = 0; j < 4; ++j){
                acc[i][j] = __builtin_amdgcn_mfma_f32_16x16x32_bf16(a[i], b[j], acc[i][j], 0, 0, 0);
            }
        }
        __syncthreads();
    }

    // C/D layout: col = lane&15, row = q*4 + reg  [measured mapping]
    #pragma unroll
    for (int i = 0; i < 4; ++i){
        const int row0 = mBase + wr*64 + i*16 + q*4;
        #pragma unroll
        for (int j = 0; j < 4; ++j){
            const int col = nBase + wc*64 + j*16 + m16;
            bf16_t* Cp = C + (size_t)row0 * N + col;
            #pragma unroll
            for (int r = 0; r < 4; ++r)
                Cp[(size_t)r * N] = (bf16_t)acc[i][j][r];
        }
    }
}

// ---------- aggregation: one wave per node ----------
// layer 1: H[i] = relu(sum_e norm*T[src] + dinv[i]^2*T[i] + b), D=512, bf16 out
__global__ __launch_bounds__(256)
void agg_bias_relu_512(const bf16_t* __restrict__ T, const int* __restrict__ rowp,
                       const int* __restrict__ csrc, const float* __restrict__ cnorm,
                       const float* __restrict__ dinv, const float* __restrict__ bias,
                       bf16_t* __restrict__ H)
{
    const int gw   = (blockIdx.x * 256 + threadIdx.x) >> 6;
    const int lane = threadIdx.x & 63;
    if (gw >= N_NODES) return;
    const float di = dinv[gw];
    float acc[8];
    {
        uint4 v = ((const uint4*)(T + (size_t)gw * 512))[lane];
        float f[8]; unpack8(v, f);
        const float w = di * di;
        #pragma unroll
        for (int j = 0; j < 8; ++j) acc[j] = w * f[j];
    }
    const int e1 = rowp[gw + 1];
    for (int e = rowp[gw]; e < e1; ++e){
        const int s   = csrc[e];
        const float w = cnorm[e];
        uint4 v = ((const uint4*)(T + (size_t)s * 512))[lane];
        float f[8]; unpack8(v, f);
        #pragma unroll
        for (int j = 0; j < 8; ++j) acc[j] += w * f[j];
    }
    const float4 b0 = ((const float4*)bias)[lane*2];
    const float4 b1 = ((const float4*)bias)[lane*2 + 1];
    float r[8] = {acc[0]+b0.x, acc[1]+b0.y, acc[2]+b0.z, acc[3]+b0.w,
                  acc[4]+b1.x, acc[5]+b1.y, acc[6]+b1.z, acc[7]+b1.w};
    uint4 o;
    o.x = f2bf_bits(fmaxf(r[0],0.f)) | (f2bf_bits(fmaxf(r[1],0.f)) << 16);
    o.y = f2bf_bits(fmaxf(r[2],0.f)) | (f2bf_bits(fmaxf(r[3],0.f)) << 16);
    o.z = f2bf_bits(fmaxf(r[4],0.f)) | (f2bf_bits(fmaxf(r[5],0.f)) << 16);
    o.w = f2bf_bits(fmaxf(r[6],0.f)) | (f2bf_bits(fmaxf(r[7],0.f)) << 16);
    ((uint4*)(H + (size_t)gw * 512))[lane] = o;
}

// layer 2: out[i] = sum_e norm*T[src] + dinv[i]^2*T[i] + b, D=256, fp32 out
__global__ __launch_bounds__(256)
void agg_bias_out_256(const bf16_t* __restrict__ T, const int* __restrict__ rowp,
                      const int* __restrict__ csrc, const float* __restrict__ cnorm,
                      const float* __restrict__ dinv, const float* __restrict__ bias,
                      float* __restrict__ out)
{
    const int gw   = (blockIdx.x * 256 + threadIdx.x) >> 6;
    const int lane = threadIdx.x & 63;
    if (gw >= N_NODES) return;
    const float di = dinv[gw];
    float acc[4];
    {
        uint2 v = ((const uint2*)(T + (size_t)gw * 256))[lane];
        float f[4]; unpack4(v, f);
        const float w = di * di;
        #pragma unroll
        for (int j = 0; j < 4; ++j) acc[j] = w * f[j];
    }
    const int e1 = rowp[gw + 1];
    for (int e = rowp[gw]; e < e1; ++e){
        const int s   = csrc[e];
        const float w = cnorm[e];
        uint2 v = ((const uint2*)(T + (size_t)s * 256))[lane];
        float f[4]; unpack4(v, f);
        #pragma unroll
        for (int j = 0; j < 4; ++j) acc[j] += w * f[j];
    }
    const float4 b = ((const float4*)bias)[lane];
    float4 o = {acc[0]+b.x, acc[1]+b.y, acc[2]+b.z, acc[3]+b.w};
    ((float4*)(out + (size_t)gw * 256))[lane] = o;
}

// ---------- host ----------
extern "C" void kernel_launch(void* const* d_in, const int* in_sizes, int n_in,
                              void* d_out, int out_size, void* d_ws, size_t ws_size,
                              hipStream_t stream)
{
    const float* x  = (const float*)d_in[0];
    const int*   ei = (const int*)d_in[1];     // [0..4e5)=src, [4e5..8e5)=dst
    const float* W1 = (const float*)d_in[2];
    const float* b1 = (const float*)d_in[3];
    const float* W2 = (const float*)d_in[4];
    const float* b2 = (const float*)d_in[5];
    float* out = (float*)d_out;

    // workspace carve (256B aligned)
    char* w = (char*)d_ws;
    auto alloc = [&](size_t bytes) -> char* {
        char* p = w; w += (bytes + 255) & ~(size_t)255; return p;
    };
    bf16_t* Xb    = (bf16_t*)alloc((size_t)M_PAD * 512 * 2);  // Xb, later reused as H
    bf16_t* T     = (bf16_t*)alloc((size_t)M_PAD * 512 * 2);  // T1, later reused as T2
    bf16_t* W1t   = (bf16_t*)alloc(512 * 512 * 2);
    bf16_t* W2t   = (bf16_t*)alloc(256 * 512 * 2);
    int*    deg   = (int*)  alloc(N_NODES * 4);
    float*  dinv  = (float*)alloc(N_NODES * 4);
    int*    rowp  = (int*)  alloc((N_NODES + 1) * 4);
    int*    cursor= (int*)  alloc(N_NODES * 4);
    int*    part  = (int*)  alloc(N_NODES * 4);
    int*    bsum  = (int*)  alloc(NB_SCAN * 4);
    int*    bsum2 = (int*)  alloc(NB_SCAN * 4);
    int*    csrc  = (int*)  alloc(N_EDGES * 4);
    float*  cnorm = (float*)alloc(N_EDGES * 4);

    // dtype conversion
    conv_x_bf16<<<(M_PAD*128)/256, 256, 0, stream>>>(x, Xb);
    conv_w_t  <<<(512*512)/256,   256, 0, stream>>>(W1, W1t, 512);
    conv_w_t  <<<(256*512)/256,   256, 0, stream>>>(W2, W2t, 256);

    // degree + CSR (group edges by dst; self-loops handled analytically)
    k_init_deg<<<NB_SCAN, 256, 0, stream>>>(deg);
    k_count   <<<(N_EDGES+255)/256, 256, 0, stream>>>(ei, deg);
    k_dinv    <<<NB_SCAN, 256, 0, stream>>>(deg, dinv);
    k_scan_block<<<NB_SCAN, 256, 0, stream>>>(deg, part, bsum, N_NODES);
    k_scan_bsum <<<1, 256, 0, stream>>>(bsum, bsum2, NB_SCAN);
    k_finalize_rowptr<<<NB_SCAN, 256, 0, stream>>>(part, bsum2, rowp, cursor, N_NODES);
    k_place   <<<(N_EDGES+255)/256, 256, 0, stream>>>(ei, dinv, cursor, csrc, cnorm);

    // layer 1: T1 = Xb @ W1 ; H = relu(agg(T1) + b1)   (H reuses Xb buffer)
    gemm_bf16_mfma<<<dim3(M_PAD/128, 512/128), 256, 0, stream>>>(Xb, W1t, T, 512, 512);
    agg_bias_relu_512<<<(N_NODES+3)/4, 256, 0, stream>>>(T, rowp, csrc, cnorm, dinv, b1, Xb);

    // layer 2: T2 = H @ W2 ; out = agg(T2) + b2        (T2 reuses T buffer)
    gemm_bf16_mfma<<<dim3(M_PAD/128, 256/128), 256, 0, stream>>>(Xb, W2t, T, 256, 512);
    agg_bias_out_256<<<(N_NODES+3)/4, 256, 0, stream>>>(T, rowp, csrc, cnorm, dinv, b2, out);
}

// Round 2
// 399.534 us; speedup vs baseline: 1.0577x; 1.0577x over previous
//
#include <hip/hip_runtime.h>
#include <stdint.h>

typedef __bf16 bf16_t;
typedef __bf16 bf16x8 __attribute__((ext_vector_type(8)));
typedef float f32x4 __attribute__((ext_vector_type(4)));

#define N_NODES  50000
#define N_EDGES  400000
#define D_IN     512
#define D_HID    512
#define D_OUTD   256
#define M_PAD    50048   // 391 * 128 (GEMM M padded; pad rows zeroed)
#define NB_SCAN  196     // ceil(50000/256)

// ---------- helpers ----------
__device__ __forceinline__ uint32_t f2bf_bits(float x){
    uint32_t u = __float_as_uint(x);
    return (u + 0x7fffu + ((u >> 16) & 1u)) >> 16;   // RNE
}
__device__ __forceinline__ void unpack8(uint4 v, float* f){
    f[0]=__uint_as_float(v.x<<16); f[1]=__uint_as_float(v.x & 0xffff0000u);
    f[2]=__uint_as_float(v.y<<16); f[3]=__uint_as_float(v.y & 0xffff0000u);
    f[4]=__uint_as_float(v.z<<16); f[5]=__uint_as_float(v.z & 0xffff0000u);
    f[6]=__uint_as_float(v.w<<16); f[7]=__uint_as_float(v.w & 0xffff0000u);
}
__device__ __forceinline__ void glds16(const bf16_t* g, bf16_t* l){
    __builtin_amdgcn_global_load_lds(
        (const __attribute__((address_space(1))) uint32_t*)g,
        (__attribute__((address_space(3))) uint32_t*)l, 16, 0, 0);
}

// ---------- dtype conversion ----------
__global__ __launch_bounds__(256)
void conv_x_bf16(const float* __restrict__ x, bf16_t* __restrict__ Xb){
    const int t = blockIdx.x * 256 + threadIdx.x;   // 4 elements per thread
    const int row = t >> 7;                          // (4t)/512
    uint2 o;
    if (row < N_NODES){
        float4 v = ((const float4*)x)[t];
        o.x = f2bf_bits(v.x) | (f2bf_bits(v.y) << 16);
        o.y = f2bf_bits(v.z) | (f2bf_bits(v.w) << 16);
    } else { o.x = 0u; o.y = 0u; }                   // zero pad rows
    ((uint2*)Xb)[t] = o;
}

// Both weight transposes in one launch:
// n in [0,512): W1t[n][k] = bf16(W1[k][n]) (ncols 512)
// n in [512,768): W2t[n-512][k] = bf16(W2[k][n-512]) (ncols 256)
__global__ __launch_bounds__(256)
void conv_w_both(const float* __restrict__ W1, const float* __restrict__ W2,
                 bf16_t* __restrict__ W1t, bf16_t* __restrict__ W2t){
    const int idx = blockIdx.x * 256 + threadIdx.x;  // n*512 + k
    const int n = idx >> 9;
    const int k = idx & 511;
    if (n < 512) W1t[idx] = (bf16_t)W1[k * 512 + n];
    else         W2t[(n - 512) * 512 + k] = (bf16_t)W2[k * 256 + (n - 512)];
}

// ---------- degree / CSR build ----------
__global__ __launch_bounds__(256)
void k_init_deg(int* __restrict__ deg){
    int i = blockIdx.x*256 + threadIdx.x;
    if (i < N_NODES) deg[i] = 1;                     // self-loop
}
__global__ __launch_bounds__(256)
void k_count(const int* __restrict__ ei, int* __restrict__ deg){
    int e = blockIdx.x*256 + threadIdx.x;
    if (e < N_EDGES) atomicAdd(&deg[ei[N_EDGES + e]], 1);
}
__global__ __launch_bounds__(256)
void k_dinv(const int* __restrict__ deg, float* __restrict__ dinv){
    int i = blockIdx.x*256 + threadIdx.x;
    if (i < N_NODES) dinv[i] = rsqrtf((float)deg[i]);
}
// block-local exclusive scan of (deg-1)
__global__ __launch_bounds__(256)
void k_scan_block(const int* __restrict__ deg, int* __restrict__ part,
                  int* __restrict__ bsum, int n){
    __shared__ int tmp[256];
    int i = blockIdx.x*256 + threadIdx.x;
    int v = (i < n) ? (deg[i] - 1) : 0;
    tmp[threadIdx.x] = v;
    __syncthreads();
    for (int off = 1; off < 256; off <<= 1){
        int t = (threadIdx.x >= off) ? tmp[threadIdx.x - off] : 0;
        __syncthreads();
        tmp[threadIdx.x] += t;
        __syncthreads();
    }
    if (i < n) part[i] = tmp[threadIdx.x] - v;
    if (threadIdx.x == 255) bsum[blockIdx.x] = tmp[255];
}
__global__ __launch_bounds__(256)
void k_scan_bsum(const int* __restrict__ bsum, int* __restrict__ bsum2, int nb){
    __shared__ int tmp[256];
    int v = (threadIdx.x < nb) ? bsum[threadIdx.x] : 0;
    tmp[threadIdx.x] = v;
    __syncthreads();
    for (int off = 1; off < 256; off <<= 1){
        int t = (threadIdx.x >= off) ? tmp[threadIdx.x - off] : 0;
        __syncthreads();
        tmp[threadIdx.x] += t;
        __syncthreads();
    }
    if (threadIdx.x < nb) bsum2[threadIdx.x] = tmp[threadIdx.x] - v;
}
__global__ __launch_bounds__(256)
void k_finalize_rowptr(const int* __restrict__ part, const int* __restrict__ bsum2,
                       int* __restrict__ rowp, int* __restrict__ cursor, int n){
    int i = blockIdx.x*256 + threadIdx.x;
    if (i < n){ int r = part[i] + bsum2[blockIdx.x]; rowp[i] = r; cursor[i] = r; }
    if (i == 0) rowp[n] = N_EDGES;
}
__global__ __launch_bounds__(256)
void k_place(const int* __restrict__ ei, const float* __restrict__ dinv,
             int* __restrict__ cursor, int* __restrict__ csrc, float* __restrict__ cnorm){
    int e = blockIdx.x*256 + threadIdx.x;
    if (e < N_EDGES){
        int s = ei[e];
        int d = ei[N_EDGES + e];
        int p = atomicAdd(&cursor[d], 1);
        csrc[p]  = s;
        cnorm[p] = dinv[s] * dinv[d];
    }
}

// ---------- bf16 MFMA GEMM: C[M_PAD][N] = A[M_PAD][K] @ Bt[N][K]^T ----------
// 128x128 tile, BK=32, 256 threads = 4 waves in 2x2, each wave 64x64 (4x4 MFMA 16x16x32)
__global__ __launch_bounds__(256, 2)
void gemm_bf16_mfma(const bf16_t* __restrict__ A, const bf16_t* __restrict__ Bt,
                    bf16_t* __restrict__ C, int N, int K)
{
    __shared__ bf16_t As[128*32];   // [m][k], 8 KB
    __shared__ bf16_t Bs[128*32];   // [n][k], 8 KB

    const int tid  = threadIdx.x;
    const int wave = tid >> 6;
    const int lane = tid & 63;
    const int wr = wave >> 1;
    const int wc = wave & 1;
    const int mBase = blockIdx.x * 128;
    const int nBase = blockIdx.y * 128;

    // staging: wave-uniform LDS base + lane*16B; lane l -> row base+l/4, k-part (l%4)*8
    const int srow = lane >> 2;
    const int scol = (lane & 3) << 3;
    const bf16_t* Ag0 = A  + (size_t)(mBase + wave*16 + srow) * K + scol;
    const bf16_t* Ag1 = Ag0 + (size_t)64 * K;
    const bf16_t* Bg0 = Bt + (size_t)(nBase + wave*16 + srow) * K + scol;
    const bf16_t* Bg1 = Bg0 + (size_t)64 * K;
    bf16_t* As0 = &As[wave*512];
    bf16_t* As1 = &As[wave*512 + 64*32];
    bf16_t* Bs0 = &Bs[wave*512];
    bf16_t* Bs1 = &Bs[wave*512 + 64*32];

    // fragment addressing: A[m=lane&15][k=q*8+j], B[k=q*8+j][n=lane&15]
    const int m16 = lane & 15;
    const int q   = lane >> 4;
    const bf16_t* aP = &As[(wr*64 + m16)*32 + q*8];
    const bf16_t* bP = &Bs[(wc*64 + m16)*32 + q*8];

    f32x4 acc[4][4] = {};

    for (int k0 = 0; k0 < K; k0 += 32){
        glds16(Ag0 + k0, As0);
        glds16(Ag1 + k0, As1);
        glds16(Bg0 + k0, Bs0);
        glds16(Bg1 + k0, Bs1);
        __syncthreads();           // drains vmcnt for global_load_lds
        bf16x8 a[4], b[4];
        #pragma unroll
        for (int t = 0; t < 4; ++t){
            a[t] = *(const bf16x8*)(aP + t*16*32);
            b[t] = *(const bf16x8*)(bP + t*16*32);
        }
        #pragma unroll
        for (int i = 0; i < 4; ++i){
            #pragma unroll
            for (int j = 0; j < 4; ++j){
                acc[i][j] = __builtin_amdgcn_mfma_f32_16x16x32_bf16(a[i], b[j], acc[i][j], 0, 0, 0);
            }
        }
        __syncthreads();
    }

    // C/D layout: col = lane&15, row = q*4 + reg  [measured mapping]
    #pragma unroll
    for (int i = 0; i < 4; ++i){
        const int row0 = mBase + wr*64 + i*16 + q*4;
        #pragma unroll
        for (int j = 0; j < 4; ++j){
            const int col = nBase + wc*64 + j*16 + m16;
            bf16_t* Cp = C + (size_t)row0 * N + col;
            #pragma unroll
            for (int r = 0; r < 4; ++r)
                Cp[(size_t)r * N] = (bf16_t)acc[i][j][r];
        }
    }
}

// ---------- aggregation ----------
// layer 1: H[i] = relu(sum_e norm*T[src] + dinv[i]^2*T[i] + b), D=512, bf16 out
// one wave per node; edge loop unrolled x4 so 4 row-gathers are in flight.
__global__ __launch_bounds__(256)
void agg_bias_relu_512(const bf16_t* __restrict__ T, const int* __restrict__ rowp,
                       const int* __restrict__ csrc, const float* __restrict__ cnorm,
                       const float* __restrict__ dinv, const float* __restrict__ bias,
                       bf16_t* __restrict__ H)
{
    const int gw   = (blockIdx.x * 256 + threadIdx.x) >> 6;
    const int lane = threadIdx.x & 63;
    if (gw >= N_NODES) return;
    const float di = dinv[gw];
    float acc[8];
    {
        uint4 v = ((const uint4*)(T + (size_t)gw * 512))[lane];
        float f[8]; unpack8(v, f);
        const float w = di * di;
        #pragma unroll
        for (int j = 0; j < 8; ++j) acc[j] = w * f[j];
    }
    int e = rowp[gw];
    const int e1 = rowp[gw + 1];
    for (; e + 4 <= e1; e += 4){
        const int   s0 = csrc[e],   s1 = csrc[e+1], s2 = csrc[e+2], s3 = csrc[e+3];
        const float w0 = cnorm[e],  w1 = cnorm[e+1], w2 = cnorm[e+2], w3 = cnorm[e+3];
        uint4 v0 = ((const uint4*)(T + (size_t)s0 * 512))[lane];
        uint4 v1 = ((const uint4*)(T + (size_t)s1 * 512))[lane];
        uint4 v2 = ((const uint4*)(T + (size_t)s2 * 512))[lane];
        uint4 v3 = ((const uint4*)(T + (size_t)s3 * 512))[lane];
        float f[8];
        unpack8(v0, f);
        #pragma unroll
        for (int j = 0; j < 8; ++j) acc[j] += w0 * f[j];
        unpack8(v1, f);
        #pragma unroll
        for (int j = 0; j < 8; ++j) acc[j] += w1 * f[j];
        unpack8(v2, f);
        #pragma unroll
        for (int j = 0; j < 8; ++j) acc[j] += w2 * f[j];
        unpack8(v3, f);
        #pragma unroll
        for (int j = 0; j < 8; ++j) acc[j] += w3 * f[j];
    }
    for (; e < e1; ++e){
        const int   s = csrc[e];
        const float w = cnorm[e];
        uint4 v = ((const uint4*)(T + (size_t)s * 512))[lane];
        float f[8]; unpack8(v, f);
        #pragma unroll
        for (int j = 0; j < 8; ++j) acc[j] += w * f[j];
    }
    const float4 b0 = ((const float4*)bias)[lane*2];
    const float4 b1 = ((const float4*)bias)[lane*2 + 1];
    float r[8] = {acc[0]+b0.x, acc[1]+b0.y, acc[2]+b0.z, acc[3]+b0.w,
                  acc[4]+b1.x, acc[5]+b1.y, acc[6]+b1.z, acc[7]+b1.w};
    uint4 o;
    o.x = f2bf_bits(fmaxf(r[0],0.f)) | (f2bf_bits(fmaxf(r[1],0.f)) << 16);
    o.y = f2bf_bits(fmaxf(r[2],0.f)) | (f2bf_bits(fmaxf(r[3],0.f)) << 16);
    o.z = f2bf_bits(fmaxf(r[4],0.f)) | (f2bf_bits(fmaxf(r[5],0.f)) << 16);
    o.w = f2bf_bits(fmaxf(r[6],0.f)) | (f2bf_bits(fmaxf(r[7],0.f)) << 16);
    ((uint4*)(H + (size_t)gw * 512))[lane] = o;
}

// layer 2: out[i] = sum_e norm*T[src] + dinv[i]^2*T[i] + b, D=256, fp32 out.
// TWO nodes per wave (half-wave of 32 lanes x 16B = one 256-elem bf16 row),
// edge loop unrolled x4.
__global__ __launch_bounds__(256)
void agg_bias_out_256(const bf16_t* __restrict__ T, const int* __restrict__ rowp,
                      const int* __restrict__ csrc, const float* __restrict__ cnorm,
                      const float* __restrict__ dinv, const float* __restrict__ bias,
                      float* __restrict__ out)
{
    const int wid  = (blockIdx.x * 256 + threadIdx.x) >> 6;
    const int half = (threadIdx.x >> 5) & 1;
    const int l32  = threadIdx.x & 31;
    const int node = wid * 2 + half;
    if (node >= N_NODES) return;
    const float di = dinv[node];
    float acc[8];
    {
        uint4 v = ((const uint4*)(T + (size_t)node * 256))[l32];
        float f[8]; unpack8(v, f);
        const float w = di * di;
        #pragma unroll
        for (int j = 0; j < 8; ++j) acc[j] = w * f[j];
    }
    int e = rowp[node];
    const int e1 = rowp[node + 1];
    for (; e + 4 <= e1; e += 4){
        const int   s0 = csrc[e],   s1 = csrc[e+1], s2 = csrc[e+2], s3 = csrc[e+3];
        const float w0 = cnorm[e],  w1 = cnorm[e+1], w2 = cnorm[e+2], w3 = cnorm[e+3];
        uint4 v0 = ((const uint4*)(T + (size_t)s0 * 256))[l32];
        uint4 v1 = ((const uint4*)(T + (size_t)s1 * 256))[l32];
        uint4 v2 = ((const uint4*)(T + (size_t)s2 * 256))[l32];
        uint4 v3 = ((const uint4*)(T + (size_t)s3 * 256))[l32];
        float f[8];
        unpack8(v0, f);
        #pragma unroll
        for (int j = 0; j < 8; ++j) acc[j] += w0 * f[j];
        unpack8(v1, f);
        #pragma unroll
        for (int j = 0; j < 8; ++j) acc[j] += w1 * f[j];
        unpack8(v2, f);
        #pragma unroll
        for (int j = 0; j < 8; ++j) acc[j] += w2 * f[j];
        unpack8(v3, f);
        #pragma unroll
        for (int j = 0; j < 8; ++j) acc[j] += w3 * f[j];
    }
    for (; e < e1; ++e){
        const int   s = csrc[e];
        const float w = cnorm[e];
        uint4 v = ((const uint4*)(T + (size_t)s * 256))[l32];
        float f[8]; unpack8(v, f);
        #pragma unroll
        for (int j = 0; j < 8; ++j) acc[j] += w * f[j];
    }
    const float4 b0 = ((const float4*)bias)[l32*2];
    const float4 b1 = ((const float4*)bias)[l32*2 + 1];
    float4 o0 = {acc[0]+b0.x, acc[1]+b0.y, acc[2]+b0.z, acc[3]+b0.w};
    float4 o1 = {acc[4]+b1.x, acc[5]+b1.y, acc[6]+b1.z, acc[7]+b1.w};
    ((float4*)(out + (size_t)node * 256))[l32*2]     = o0;
    ((float4*)(out + (size_t)node * 256))[l32*2 + 1] = o1;
}

// ---------- host ----------
extern "C" void kernel_launch(void* const* d_in, const int* in_sizes, int n_in,
                              void* d_out, int out_size, void* d_ws, size_t ws_size,
                              hipStream_t stream)
{
    const float* x  = (const float*)d_in[0];
    const int*   ei = (const int*)d_in[1];     // [0..4e5)=src, [4e5..8e5)=dst
    const float* W1 = (const float*)d_in[2];
    const float* b1 = (const float*)d_in[3];
    const float* W2 = (const float*)d_in[4];
    const float* b2 = (const float*)d_in[5];
    float* out = (float*)d_out;

    // workspace carve (256B aligned)
    char* w = (char*)d_ws;
    auto alloc = [&](size_t bytes) -> char* {
        char* p = w; w += (bytes + 255) & ~(size_t)255; return p;
    };
    bf16_t* Xb    = (bf16_t*)alloc((size_t)M_PAD * 512 * 2);  // Xb, later reused as H
    bf16_t* T     = (bf16_t*)alloc((size_t)M_PAD * 512 * 2);  // T1, later reused as T2
    bf16_t* W1t   = (bf16_t*)alloc(512 * 512 * 2);
    bf16_t* W2t   = (bf16_t*)alloc(256 * 512 * 2);
    int*    deg   = (int*)  alloc(N_NODES * 4);
    float*  dinv  = (float*)alloc(N_NODES * 4);
    int*    rowp  = (int*)  alloc((N_NODES + 1) * 4);
    int*    cursor= (int*)  alloc(N_NODES * 4);
    int*    part  = (int*)  alloc(N_NODES * 4);
    int*    bsum  = (int*)  alloc(NB_SCAN * 4);
    int*    bsum2 = (int*)  alloc(NB_SCAN * 4);
    int*    csrc  = (int*)  alloc(N_EDGES * 4);
    float*  cnorm = (float*)alloc(N_EDGES * 4);

    // dtype conversion
    conv_x_bf16<<<(M_PAD*128)/256, 256, 0, stream>>>(x, Xb);
    conv_w_both<<<(768*512)/256, 256, 0, stream>>>(W1, W2, W1t, W2t);

    // degree + CSR (group edges by dst; self-loops handled analytically)
    k_init_deg<<<NB_SCAN, 256, 0, stream>>>(deg);
    k_count   <<<(N_EDGES+255)/256, 256, 0, stream>>>(ei, deg);
    k_dinv    <<<NB_SCAN, 256, 0, stream>>>(deg, dinv);
    k_scan_block<<<NB_SCAN, 256, 0, stream>>>(deg, part, bsum, N_NODES);
    k_scan_bsum <<<1, 256, 0, stream>>>(bsum, bsum2, NB_SCAN);
    k_finalize_rowptr<<<NB_SCAN, 256, 0, stream>>>(part, bsum2, rowp, cursor, N_NODES);
    k_place   <<<(N_EDGES+255)/256, 256, 0, stream>>>(ei, dinv, cursor, csrc, cnorm);

    // layer 1: T1 = Xb @ W1 ; H = relu(agg(T1) + b1)   (H reuses Xb buffer)
    gemm_bf16_mfma<<<dim3(M_PAD/128, 512/128), 256, 0, stream>>>(Xb, W1t, T, 512, 512);
    agg_bias_relu_512<<<(N_NODES+3)/4, 256, 0, stream>>>(T, rowp, csrc, cnorm, dinv, b1, Xb);

    // layer 2: T2 = H @ W2 ; out = agg(T2) + b2        (T2 reuses T buffer)
    gemm_bf16_mfma<<<dim3(M_PAD/128, 256/128), 256, 0, stream>>>(Xb, W2t, T, 256, 512);
    agg_bias_out_256<<<(25000+3)/4, 256, 0, stream>>>(T, rowp, csrc, cnorm, dinv, b2, out);
}